// Round 2
// 234.980 us; speedup vs baseline: 1.2343x; 1.2343x over previous
//
#include <hip/hip_runtime.h>

// LinearAttention fused, MFMA (bf16 in / fp32 acc).
//   kW: zero O/Zg accumulators + pre-convert w_qkv (384x64) -> bf16
//   kA: LN1 -> k,v GEMM -> exp(k) -> ctx partial = ek @ v^T  (per 256-col block)
//       LDS aliased: xn staging region reused for ek/v tiles -> 37.9 KiB -> 3 blocks/CU
//       Z partials atomicAdd'ed straight into Zg (256 locations, ~131K atomics total)
//   kR1: coalesced panel reduction of ctx partials -> atomicAdd into O (8-way contention)
//   kM: Mg[b][h][o][dd] = (1/Z) * sum_e wout[o, h*32+e] * ctx[b][h][dd][e], bf16 out
//   kB: LN1 -> q GEMM -> softmax(d)*scale -> y = M @ qs -> +b_out -> LN2
//       LDS aliased: xn region reused for qs -> 37.6 KiB -> 3 blocks/CU
#define NCOL 131072
#define CH 64

typedef float floatx4 __attribute__((ext_vector_type(4)));
typedef __bf16 bf16x8 __attribute__((ext_vector_type(8)));
typedef unsigned int u32x4 __attribute__((ext_vector_type(4)));
typedef unsigned int u32x2 __attribute__((ext_vector_type(2)));

union FragU { u32x4 q; bf16x8 v; unsigned short us[8]; };

__device__ __forceinline__ unsigned short bfb(float f){
  union { __bf16 h; unsigned short s; } u; u.h = (__bf16)f; return u.s;
}
__device__ __forceinline__ float bf2f(unsigned short h){
  union { unsigned u; float f; } x{(unsigned)h << 16};
  return x.f;
}

// LN over 64 channels for column (thread t), write bf16 column to xn_s[t][0..63], stride 72.
__device__ __forceinline__ void ln_stage(const float* __restrict__ xp,
    const float* __restrict__ g, const float* __restrict__ bb,
    unsigned short* __restrict__ xn_s, int t)
{
  float xv[64]; float s = 0.f, ss = 0.f;
  #pragma unroll
  for (int c = 0; c < 64; c++){ float u = xp[(long)c*NCOL]; xv[c] = u; s += u; ss = fmaf(u,u,ss); }
  const float mean = s * (1.f/64.f);
  const float rstd = rsqrtf(ss * (1.f/64.f) - mean*mean + 1e-5f);
  #pragma unroll
  for (int c = 0; c < 64; c++) xv[c] = (xv[c]-mean)*rstd*g[c] + bb[c];
  #pragma unroll
  for (int j = 0; j < 8; j++){
    FragU u;
    #pragma unroll
    for (int e = 0; e < 8; e++) u.v[e] = (__bf16)xv[j*8+e];
    *(u32x4*)(xn_s + t*72 + j*8) = u.q;
  }
}

// ---------------- kW: prep (zero accumulators, convert wqkv to bf16) ----------------
__global__ __launch_bounds__(256) void kW(
    const float* __restrict__ wqkv, unsigned short* __restrict__ wbf, float* __restrict__ Oz)
{
  const int i = blockIdx.x*256 + threadIdx.x;   // grid 96 -> 24576 == 384*64
  wbf[i] = bfb(wqkv[i]);
  if (i < 8448) Oz[i] = 0.f;                    // O (8192) + Zg (256)
}

// ---------------- kA ----------------
__global__ __launch_bounds__(256) void kA(
    const float* __restrict__ x, const float* __restrict__ g1, const float* __restrict__ b1,
    const unsigned short* __restrict__ wbf, float* __restrict__ pctx, float* __restrict__ Zg)
{
  __shared__ __align__(16) char smem[37888];
  unsigned short* xn_s = (unsigned short*)smem;             // [0,36864) staging only (dead after bx)
  unsigned short* ek_s = (unsigned short*)smem;             // [0,16896)   alias
  unsigned short* v_s  = (unsigned short*)(smem + 16896);   // [16896,33792) alias
  float* Zp            = (float*)(smem + 33792);            // [33792,37888)

  const int t = threadIdx.x;
  const int bid = blockIdx.x;
  const int b = bid >> 9;
  const long col0 = (long)(bid & 511) * 256;
  const int w = t >> 6, lane = t & 63, qq = lane >> 4, l16 = lane & 15;

  ln_stage(x + (long)b*CH*NCOL + col0 + t, g1, b1, xn_s, t);
  __syncthreads();

  // B fragments of xn for this wave's 4 col-tiles (wave-private cols [64w,64w+64))
  FragU bx[4][2];
  #pragma unroll
  for (int nt = 0; nt < 4; nt++)
    #pragma unroll
    for (int ks = 0; ks < 2; ks++)
      bx[nt][ks].q = *(const u32x4*)(xn_s + ((4*w+nt)*16 + l16)*72 + ks*32 + qq*8);
  __syncthreads();   // xn dead; ek_s/v_s/Zp may now overwrite the region

  floatx4 cc[4][2][2];
  #pragma unroll
  for (int h = 0; h < 4; h++)
    #pragma unroll
    for (int dt = 0; dt < 2; dt++)
      #pragma unroll
      for (int et = 0; et < 2; et++)
        cc[h][dt][et] = floatx4{0.f,0.f,0.f,0.f};

  #pragma unroll
  for (int h = 0; h < 4; h++){
    // k (rt 0,1) and v (rt 2,3) GEMM, 16 rows per rt; A-frags are pre-converted bf16
    #pragma unroll
    for (int rt = 0; rt < 4; rt++){
      const int row0 = ((rt < 2) ? 128 : 256) + h*32 + (rt & 1)*16;
      const unsigned short* wr = wbf + (row0 + l16)*64 + qq*8;
      FragU a0, a1;
      a0.q = *(const u32x4*)wr;
      a1.q = *(const u32x4*)(wr + 32);
      unsigned short* dst = ((rt < 2) ? ek_s : v_s) + ((rt & 1)*16 + qq*4)*264;
      #pragma unroll
      for (int nt = 0; nt < 4; nt++){
        floatx4 c = floatx4{0.f,0.f,0.f,0.f};
        c = __builtin_amdgcn_mfma_f32_16x16x32_bf16(a0.v, bx[nt][0].v, c, 0, 0, 0);
        c = __builtin_amdgcn_mfma_f32_16x16x32_bf16(a1.v, bx[nt][1].v, c, 0, 0, 0);
        const int colb = (4*w+nt)*16 + l16;
        if (rt < 2){
          #pragma unroll
          for (int r = 0; r < 4; r++) dst[r*264 + colb] = bfb(__expf(c[r]));
        } else {
          #pragma unroll
          for (int r = 0; r < 4; r++) dst[r*264 + colb] = bfb(c[r]);
        }
      }
    }
    __syncthreads();
    // Z partials: thread sums 32 cols of row d
    {
      const int d = t & 31, part = t >> 5;
      const unsigned short* p = ek_s + d*264 + part*32;
      float zs = 0.f;
      #pragma unroll
      for (int j = 0; j < 4; j++){
        FragU u; u.q = *(const u32x4*)(p + j*8);
        #pragma unroll
        for (int e = 0; e < 8; e++) zs += bf2f(u.us[e]);
      }
      Zp[h*256 + part*32 + d] = zs;
    }
    // ctx MFMAs: D[d][e] += sum_col ek[d,col] v[e,col]; wave w covers cols [64w,64w+64)
    #pragma unroll
    for (int kk = 0; kk < 2; kk++){
      const int ks2 = 2*w + kk;
      FragU ae[2], bv[2];
      #pragma unroll
      for (int dt = 0; dt < 2; dt++) ae[dt].q = *(const u32x4*)(ek_s + (dt*16 + l16)*264 + ks2*32 + qq*8);
      #pragma unroll
      for (int et = 0; et < 2; et++) bv[et].q = *(const u32x4*)(v_s + (et*16 + l16)*264 + ks2*32 + qq*8);
      #pragma unroll
      for (int dt = 0; dt < 2; dt++)
        #pragma unroll
        for (int et = 0; et < 2; et++)
          cc[h][dt][et] = __builtin_amdgcn_mfma_f32_16x16x32_bf16(ae[dt].v, bv[et].v, cc[h][dt][et], 0, 0, 0);
    }
    __syncthreads();
  }

  // cross-wave ctx reduction, staged in 32 KiB (scr aliases ek_s/v_s; Zp untouched)
  float* scr = (float*)smem;
  if (w & 1){
    #pragma unroll
    for (int h = 0; h < 4; h++)
      #pragma unroll
      for (int dt = 0; dt < 2; dt++)
        #pragma unroll
        for (int et = 0; et < 2; et++)
          ((floatx4*)scr)[(w>>1)*1024 + (h*4 + dt*2 + et)*64 + lane] = cc[h][dt][et];
  }
  __syncthreads();
  if (!(w & 1)){
    #pragma unroll
    for (int h = 0; h < 4; h++)
      #pragma unroll
      for (int dt = 0; dt < 2; dt++)
        #pragma unroll
        for (int et = 0; et < 2; et++)
          cc[h][dt][et] += ((floatx4*)scr)[(w>>1)*1024 + (h*4 + dt*2 + et)*64 + lane];
  }
  __syncthreads();
  if (w == 2){
    #pragma unroll
    for (int h = 0; h < 4; h++)
      #pragma unroll
      for (int dt = 0; dt < 2; dt++)
        #pragma unroll
        for (int et = 0; et < 2; et++)
          ((floatx4*)scr)[(h*4 + dt*2 + et)*64 + lane] = cc[h][dt][et];
  }
  __syncthreads();
  if (w == 0){
    #pragma unroll
    for (int h = 0; h < 4; h++)
      #pragma unroll
      for (int dt = 0; dt < 2; dt++)
        #pragma unroll
        for (int et = 0; et < 2; et++){
          floatx4 r = cc[h][dt][et] + ((floatx4*)scr)[(h*4 + dt*2 + et)*64 + lane];
          *(floatx4*)(pctx + (long)bid*4096 + (h*4 + dt*2 + et)*256 + lane*4) = r;
        }
  }
  if (t < 128){
    const int h = t >> 5, d = t & 31;
    float z = 0.f;
    #pragma unroll
    for (int part = 0; part < 8; part++) z += Zp[h*256 + part*32 + d];
    atomicAdd(&Zg[b*128 + h*32 + d], z);   // 512-way over 256 locations; device-scope default
  }
}

// ---------------- kR1: coalesced partial reduction -> atomic accumulate ----------------
__global__ __launch_bounds__(256) void kR1(
    const float* __restrict__ pctx, float* __restrict__ O)
{
  const int blk = blockIdx.x;          // 256 blocks
  const int b = blk >> 7;              // 0..1
  const int part = (blk >> 4) & 7;     // 0..7   (64 pctx rows each)
  const int chunk = blk & 15;          // 0..15  (256 r-columns each)
  const int t = threadIdx.x;
  const int r = chunk*256 + t;
  const float* p = pctx + ((long)(b*512 + part*64))*4096 + r;
  float s = 0.f;
  #pragma unroll 16
  for (int row = 0; row < 64; row++) s += p[(long)row*4096];
  atomicAdd(&O[b*4096 + r], s);        // 8-way contention per location
}

// ---------------- kM: fuse w_out and 1/Z into ctx, emit bf16 ----------------
__global__ __launch_bounds__(256) void kM(
    const float* __restrict__ O, const float* __restrict__ Zg,
    const float* __restrict__ wout, unsigned short* __restrict__ Mgbf)
{
  const int idx = blockIdx.x*256 + threadIdx.x;  // 0..16383
  const int b = idx >> 13, rem = idx & 8191;
  const int h = rem >> 11, o = (rem >> 5) & 63, dd = rem & 31;
  const int dt = dd >> 4, qq = (dd >> 2) & 3, rg = dd & 3;
  float m = 0.f;
  #pragma unroll
  for (int ee = 0; ee < 32; ee++){
    const int et = ee >> 4, l16 = ee & 15;
    const int r = h*1024 + (dt*2 + et)*256 + (qq*16 + l16)*4 + rg;
    m = fmaf(wout[o*128 + h*32 + ee], O[b*4096 + r], m);
  }
  m /= Zg[b*128 + h*32 + dd];
  Mgbf[idx] = bfb(m);                  // idx == ((b*4+h)*64+o)*32+dd
}

// ---------------- kB ----------------
__global__ __launch_bounds__(256) void kB(
    const float* __restrict__ x, const float* __restrict__ g1, const float* __restrict__ b1,
    const unsigned short* __restrict__ wbf, const unsigned short* __restrict__ Mgbf,
    const float* __restrict__ bout, const float* __restrict__ g2, const float* __restrict__ b2,
    float* __restrict__ y)
{
  __shared__ __align__(16) char smem[37632];
  unsigned short* xn_s = (unsigned short*)smem;             // [0,36864) staging only (dead after bx)
  unsigned short* qs_s = (unsigned short*)smem;             // [0,20480)  alias
  float* sp            = (float*)(smem + 36864);            // 192 floats

  const int t = threadIdx.x;
  const int bid = blockIdx.x;
  const int b = bid >> 9;
  const long col0 = (long)(bid & 511) * 256;
  const int w = t >> 6, lane = t & 63, qq = lane >> 4, l16 = lane & 15;

  if (t < 64){ sp[t] = bout[t]; sp[64+t] = g2[t]; sp[128+t] = b2[t]; }
  ln_stage(x + (long)b*CH*NCOL + col0 + t, g1, b1, xn_s, t);
  __syncthreads();

  FragU bx[4][2];
  #pragma unroll
  for (int nt = 0; nt < 4; nt++)
    #pragma unroll
    for (int ks = 0; ks < 2; ks++)
      bx[nt][ks].q = *(const u32x4*)(xn_s + ((4*w+nt)*16 + l16)*72 + ks*32 + qq*8);
  __syncthreads();   // xn dead; qs_s may now overwrite the region

  floatx4 yacc[4][4];
  #pragma unroll
  for (int ot = 0; ot < 4; ot++)
    #pragma unroll
    for (int nt = 0; nt < 4; nt++)
      yacc[ot][nt] = floatx4{0.f,0.f,0.f,0.f};

  #pragma unroll
  for (int h = 0; h < 4; h++){
    // q GEMM -> exp -> qs_s[col][dd] (stride 40), packed b64 writes
    #pragma unroll
    for (int ot = 0; ot < 2; ot++){
      const int row0 = h*32 + ot*16;
      const unsigned short* wr = wbf + (row0 + l16)*64 + qq*8;
      FragU a0, a1;
      a0.q = *(const u32x4*)wr;
      a1.q = *(const u32x4*)(wr + 32);
      #pragma unroll
      for (int nt = 0; nt < 4; nt++){
        floatx4 c = floatx4{0.f,0.f,0.f,0.f};
        c = __builtin_amdgcn_mfma_f32_16x16x32_bf16(a0.v, bx[nt][0].v, c, 0, 0, 0);
        c = __builtin_amdgcn_mfma_f32_16x16x32_bf16(a1.v, bx[nt][1].v, c, 0, 0, 0);
        const int colb = (4*w+nt)*16 + l16;
        const unsigned short p0 = bfb(__expf(c[0])), p1 = bfb(__expf(c[1]));
        const unsigned short p2 = bfb(__expf(c[2])), p3 = bfb(__expf(c[3]));
        u32x2 pk; pk[0] = (unsigned)p0 | ((unsigned)p1 << 16); pk[1] = (unsigned)p2 | ((unsigned)p3 << 16);
        *(u32x2*)(qs_s + colb*40 + ot*16 + qq*4) = pk;
      }
    }
    __syncthreads();
    // per-column softmax normalize * scale (thread t owns col t)
    {
      unsigned short* p = qs_s + t*40;
      FragU u[4]; float s = 0.f;
      #pragma unroll
      for (int j = 0; j < 4; j++){
        u[j].q = *(const u32x4*)(p + j*8);
        #pragma unroll
        for (int e = 0; e < 8; e++) s += bf2f(u[j].us[e]);
      }
      const float sc = 0.17677669529663687f / s;   // 32^-0.5 / sum
      #pragma unroll
      for (int j = 0; j < 4; j++){
        #pragma unroll
        for (int e = 0; e < 8; e++) u[j].v[e] = (__bf16)(bf2f(u[j].us[e]) * sc);
        *(u32x4*)(p + j*8) = u[j].q;
      }
    }
    __syncthreads();
    // y += M_h @ qs_h  (M pre-converted bf16)
    #pragma unroll
    for (int ot = 0; ot < 4; ot++){
      FragU am;
      am.q = *(const u32x4*)(Mgbf + (((long)b*4 + h)*64 + ot*16 + l16)*32 + qq*8);
      #pragma unroll
      for (int nt = 0; nt < 4; nt++){
        FragU bq; bq.q = *(const u32x4*)(qs_s + ((4*w+nt)*16 + l16)*40 + qq*8);
        yacc[ot][nt] = __builtin_amdgcn_mfma_f32_16x16x32_bf16(am.v, bq.v, yacc[ot][nt], 0, 0, 0);
      }
    }
    __syncthreads();
  }

  // epilogue: +b_out, LN2 over 64 rows (rows live on lanes {l16, l16+16, l16+32, l16+48})
  const long ybase = (long)b*CH*NCOL;
  #pragma unroll
  for (int nt = 0; nt < 4; nt++){
    const long colg = col0 + (4*w+nt)*16 + l16;
    float vals[16]; float s = 0.f, ss = 0.f;
    #pragma unroll
    for (int ot = 0; ot < 4; ot++)
      #pragma unroll
      for (int r = 0; r < 4; r++){
        const float v = yacc[ot][nt][r] + sp[ot*16 + qq*4 + r];
        vals[ot*4+r] = v; s += v; ss = fmaf(v, v, ss);
      }
    s  += __shfl_xor(s, 16, 64);  s  += __shfl_xor(s, 32, 64);
    ss += __shfl_xor(ss, 16, 64); ss += __shfl_xor(ss, 32, 64);
    const float mean = s * (1.f/64.f);
    const float rstd = rsqrtf(ss * (1.f/64.f) - mean*mean + 1e-5f);
    #pragma unroll
    for (int ot = 0; ot < 4; ot++)
      #pragma unroll
      for (int r = 0; r < 4; r++){
        const int row = ot*16 + qq*4 + r;
        y[ybase + (long)row*NCOL + colg] = (vals[ot*4+r]-mean)*rstd*sp[64+row] + sp[128+row];
      }
  }
}

extern "C" void kernel_launch(void* const* d_in, const int* in_sizes, int n_in,
                              void* d_out, int out_size, void* d_ws, size_t ws_size,
                              hipStream_t stream)
{
  const float* x    = (const float*)d_in[0];
  const float* g1   = (const float*)d_in[1];
  const float* b1   = (const float*)d_in[2];
  const float* wqkv = (const float*)d_in[3];
  const float* wout = (const float*)d_in[4];
  const float* bout = (const float*)d_in[5];
  const float* g2   = (const float*)d_in[6];
  const float* b2   = (const float*)d_in[7];
  float* y  = (float*)d_out;
  float* ws = (float*)d_ws;

  float* pctx = ws;                          // [0, 4194304) floats
  float* O    = ws + 4194304;                // [4194304, 4202496)  (zeroed by kW)
  float* Zg   = O + 8192;                    // [4202496, 4202752)  (zeroed by kW)
  unsigned short* Mgbf = (unsigned short*)(Zg + 256);          // 16384 shorts -> ends 4210944 fl
  unsigned short* wbf  = (unsigned short*)(ws + 4210944);      // 24576 shorts -> ends 4223232 fl

  hipLaunchKernelGGL(kW,  dim3(96),   dim3(256), 0, stream, wqkv, wbf, O);
  hipLaunchKernelGGL(kA,  dim3(1024), dim3(256), 0, stream, x, g1, b1, wbf, pctx, Zg);
  hipLaunchKernelGGL(kR1, dim3(256),  dim3(256), 0, stream, pctx, O);
  hipLaunchKernelGGL(kM,  dim3(64),   dim3(256), 0, stream, O, Zg, wout, Mgbf);
  hipLaunchKernelGGL(kB,  dim3(1024), dim3(256), 0, stream, x, g1, b1, wbf, Mgbf, bout, g2, b2, y);
}

// Round 4
// 229.694 us; speedup vs baseline: 1.2627x; 1.0230x over previous
//
#include <hip/hip_runtime.h>

// LinearAttention fused, MFMA (bf16 in / fp32 acc). Wave-autonomous main loops:
// all ek/v/qs LDS tiles are wave-private in columns (wave w owns cols [64w,64w+64)),
// DS ops are in-order per wave, so the h-loops need NO __syncthreads.
//   kW: zero O/Zg accumulators + pre-convert w_qkv (384x64) -> bf16
//   kA: LN1 -> k,v GEMM -> exp(k) -> ctx partial (per 256-col block); Z accumulated
//       in-register from MFMA outputs (shfl_xor over l16), atomicAdd into Zg.
//       Barriers: 1 (alias guard) + 1 (pre-reduce) + 3 (staged ctx reduce) = 5  [was 13]
//   kR1: coalesced panel reduction of ctx partials -> atomicAdd into O
//   kM: Mg[b][h][o][dd] = (1/Z) * sum_e wout[o, h*32+e] * ctx[b][h][dd][e], bf16 out
//   kB: LN1 -> q GEMM -> softmax via shfl_xor(16/32) -> y = Mg @ qs -> +b_out -> LN2
//       Barriers: 1 (alias guard)                                            [was 13]
#define NCOL 131072
#define CH 64

typedef float floatx4 __attribute__((ext_vector_type(4)));
typedef __bf16 bf16x8 __attribute__((ext_vector_type(8)));
typedef unsigned int u32x4 __attribute__((ext_vector_type(4)));
typedef unsigned int u32x2 __attribute__((ext_vector_type(2)));

union FragU { u32x4 q; bf16x8 v; unsigned short us[8]; };

__device__ __forceinline__ unsigned short bfb(float f){
  union { __bf16 h; unsigned short s; } u; u.h = (__bf16)f; return u.s;
}
__device__ __forceinline__ float bf2f(unsigned short h){
  union { unsigned u; float f; } x{(unsigned)h << 16};
  return x.f;
}

// LN over 64 channels for column (thread t), write bf16 column to xn_s[t][0..63], stride 72.
__device__ __forceinline__ void ln_stage(const float* __restrict__ xp,
    const float* __restrict__ g, const float* __restrict__ bb,
    unsigned short* __restrict__ xn_s, int t)
{
  float xv[64]; float s = 0.f, ss = 0.f;
  #pragma unroll
  for (int c = 0; c < 64; c++){ float u = xp[(long)c*NCOL]; xv[c] = u; s += u; ss = fmaf(u,u,ss); }
  const float mean = s * (1.f/64.f);
  const float rstd = rsqrtf(ss * (1.f/64.f) - mean*mean + 1e-5f);
  #pragma unroll
  for (int c = 0; c < 64; c++) xv[c] = (xv[c]-mean)*rstd*g[c] + bb[c];
  #pragma unroll
  for (int j = 0; j < 8; j++){
    FragU u;
    #pragma unroll
    for (int e = 0; e < 8; e++) u.v[e] = (__bf16)xv[j*8+e];
    *(u32x4*)(xn_s + t*72 + j*8) = u.q;
  }
}

// ---------------- kW: prep (zero accumulators, convert wqkv to bf16) ----------------
__global__ __launch_bounds__(256) void kW(
    const float* __restrict__ wqkv, unsigned short* __restrict__ wbf, float* __restrict__ Oz)
{
  const int i = blockIdx.x*256 + threadIdx.x;   // grid 96 -> 24576 == 384*64
  wbf[i] = bfb(wqkv[i]);
  if (i < 8448) Oz[i] = 0.f;                    // O (8192) + Zg (256)
}

// ---------------- kA ----------------
__global__ __launch_bounds__(256) void kA(
    const float* __restrict__ x, const float* __restrict__ g1, const float* __restrict__ b1,
    const unsigned short* __restrict__ wbf, float* __restrict__ pctx, float* __restrict__ Zg)
{
  __shared__ __align__(16) char smem[37888];
  unsigned short* xn_s = (unsigned short*)smem;             // [0,36864) staging (dead after bx)
  unsigned short* ek_s = (unsigned short*)smem;             // [0,16896)   alias
  unsigned short* v_s  = (unsigned short*)(smem + 16896);   // [16896,33792) alias
  float* Zp            = (float*)(smem + 33792);            // [33792,35840) : [w][128]

  const int t = threadIdx.x;
  const int bid = blockIdx.x;
  const int b = bid >> 9;
  const long col0 = (long)(bid & 511) * 256;
  const int w = t >> 6, lane = t & 63, qq = lane >> 4, l16 = lane & 15;

  ln_stage(x + (long)b*CH*NCOL + col0 + t, g1, b1, xn_s, t);
  // in-wave read-back of own wave's columns (DS in-order per wave; no barrier)
  FragU bx[4][2];
  #pragma unroll
  for (int nt = 0; nt < 4; nt++)
    #pragma unroll
    for (int ks = 0; ks < 2; ks++)
      bx[nt][ks].q = *(const u32x4*)(xn_s + ((4*w+nt)*16 + l16)*72 + ks*32 + qq*8);
  __syncthreads();   // alias guard: all waves' bx loaded before ek/v overwrite xn

  floatx4 cc[4][2][2];
  #pragma unroll
  for (int h = 0; h < 4; h++)
    #pragma unroll
    for (int dt = 0; dt < 2; dt++)
      #pragma unroll
      for (int et = 0; et < 2; et++)
        cc[h][dt][et] = floatx4{0.f,0.f,0.f,0.f};

  #pragma unroll
  for (int h = 0; h < 4; h++){
    float zr[8];
    #pragma unroll
    for (int j = 0; j < 8; j++) zr[j] = 0.f;
    // k (rt 0,1) and v (rt 2,3) GEMM, 16 rows per rt; wave-private column slices
    #pragma unroll
    for (int rt = 0; rt < 4; rt++){
      const int row0 = ((rt < 2) ? 128 : 256) + h*32 + (rt & 1)*16;
      const unsigned short* wr = wbf + (row0 + l16)*64 + qq*8;
      FragU a0, a1;
      a0.q = *(const u32x4*)wr;
      a1.q = *(const u32x4*)(wr + 32);
      unsigned short* dst = ((rt < 2) ? ek_s : v_s) + ((rt & 1)*16 + qq*4)*264;
      #pragma unroll
      for (int nt = 0; nt < 4; nt++){
        floatx4 c = floatx4{0.f,0.f,0.f,0.f};
        c = __builtin_amdgcn_mfma_f32_16x16x32_bf16(a0.v, bx[nt][0].v, c, 0, 0, 0);
        c = __builtin_amdgcn_mfma_f32_16x16x32_bf16(a1.v, bx[nt][1].v, c, 0, 0, 0);
        const int colb = (4*w+nt)*16 + l16;
        if (rt < 2){
          #pragma unroll
          for (int r = 0; r < 4; r++){
            const float e = __expf(c[r]);
            dst[r*264 + colb] = bfb(e);
            zr[(rt & 1)*4 + r] += e;
          }
        } else {
          #pragma unroll
          for (int r = 0; r < 4; r++) dst[r*264 + colb] = bfb(c[r]);
        }
      }
    }
    // Z partial for this wave's 64 cols: butterfly over l16 lanes
    #pragma unroll
    for (int j = 0; j < 8; j++){
      float v = zr[j];
      v += __shfl_xor(v, 1, 64); v += __shfl_xor(v, 2, 64);
      v += __shfl_xor(v, 4, 64); v += __shfl_xor(v, 8, 64);
      if (l16 == 0) Zp[w*128 + h*32 + (j >> 2)*16 + qq*4 + (j & 3)] = v;
    }
    // ctx MFMAs: wave w covers its own cols [64w,64w+64); in-wave DS ordering
    #pragma unroll
    for (int kk = 0; kk < 2; kk++){
      const int ks2 = 2*w + kk;
      FragU ae[2], bv[2];
      #pragma unroll
      for (int dt = 0; dt < 2; dt++) ae[dt].q = *(const u32x4*)(ek_s + (dt*16 + l16)*264 + ks2*32 + qq*8);
      #pragma unroll
      for (int et = 0; et < 2; et++) bv[et].q = *(const u32x4*)(v_s + (et*16 + l16)*264 + ks2*32 + qq*8);
      #pragma unroll
      for (int dt = 0; dt < 2; dt++)
        #pragma unroll
        for (int et = 0; et < 2; et++)
          cc[h][dt][et] = __builtin_amdgcn_mfma_f32_16x16x32_bf16(ae[dt].v, bv[et].v, cc[h][dt][et], 0, 0, 0);
    }
  }
  __syncthreads();   // all waves done with ek/v and Zp writes

  if (t < 128){
    const float z = Zp[t] + Zp[128 + t] + Zp[256 + t] + Zp[384 + t];
    atomicAdd(&Zg[b*128 + t], z);   // t == h*32+d
  }

  // cross-wave ctx reduction, staged in 32 KiB (scr aliases ek_s/v_s; Zp untouched)
  float* scr = (float*)smem;
  if (w & 1){
    #pragma unroll
    for (int h = 0; h < 4; h++)
      #pragma unroll
      for (int dt = 0; dt < 2; dt++)
        #pragma unroll
        for (int et = 0; et < 2; et++)
          ((floatx4*)scr)[(w>>1)*1024 + (h*4 + dt*2 + et)*64 + lane] = cc[h][dt][et];
  }
  __syncthreads();
  if (!(w & 1)){
    #pragma unroll
    for (int h = 0; h < 4; h++)
      #pragma unroll
      for (int dt = 0; dt < 2; dt++)
        #pragma unroll
        for (int et = 0; et < 2; et++)
          cc[h][dt][et] += ((floatx4*)scr)[(w>>1)*1024 + (h*4 + dt*2 + et)*64 + lane];
  }
  __syncthreads();
  if (w == 2){
    #pragma unroll
    for (int h = 0; h < 4; h++)
      #pragma unroll
      for (int dt = 0; dt < 2; dt++)
        #pragma unroll
        for (int et = 0; et < 2; et++)
          ((floatx4*)scr)[(h*4 + dt*2 + et)*64 + lane] = cc[h][dt][et];
  }
  __syncthreads();
  if (w == 0){
    #pragma unroll
    for (int h = 0; h < 4; h++)
      #pragma unroll
      for (int dt = 0; dt < 2; dt++)
        #pragma unroll
        for (int et = 0; et < 2; et++){
          floatx4 r = cc[h][dt][et] + ((floatx4*)scr)[(h*4 + dt*2 + et)*64 + lane];
          *(floatx4*)(pctx + (long)bid*4096 + (h*4 + dt*2 + et)*256 + lane*4) = r;
        }
  }
}

// ---------------- kR1: coalesced partial reduction -> atomic accumulate ----------------
__global__ __launch_bounds__(256) void kR1(
    const float* __restrict__ pctx, float* __restrict__ O)
{
  const int blk = blockIdx.x;          // 256 blocks
  const int b = blk >> 7;              // 0..1
  const int part = (blk >> 4) & 7;     // 0..7   (64 pctx rows each)
  const int chunk = blk & 15;          // 0..15  (256 r-columns each)
  const int t = threadIdx.x;
  const int r = chunk*256 + t;
  const float* p = pctx + ((long)(b*512 + part*64))*4096 + r;
  float s = 0.f;
  #pragma unroll 16
  for (int row = 0; row < 64; row++) s += p[(long)row*4096];
  atomicAdd(&O[b*4096 + r], s);        // 8-way contention per location
}

// ---------------- kM: fuse w_out and 1/Z into ctx, emit bf16 ----------------
__global__ __launch_bounds__(256) void kM(
    const float* __restrict__ O, const float* __restrict__ Zg,
    const float* __restrict__ wout, unsigned short* __restrict__ Mgbf)
{
  const int idx = blockIdx.x*256 + threadIdx.x;  // 0..16383
  const int b = idx >> 13, rem = idx & 8191;
  const int h = rem >> 11, o = (rem >> 5) & 63, dd = rem & 31;
  const int dt = dd >> 4, qq = (dd >> 2) & 3, rg = dd & 3;
  float m = 0.f;
  #pragma unroll
  for (int ee = 0; ee < 32; ee++){
    const int et = ee >> 4, l16 = ee & 15;
    const int r = h*1024 + (dt*2 + et)*256 + (qq*16 + l16)*4 + rg;
    m = fmaf(wout[o*128 + h*32 + ee], O[b*4096 + r], m);
  }
  m /= Zg[b*128 + h*32 + dd];
  Mgbf[idx] = bfb(m);                  // idx == ((b*4+h)*64+o)*32+dd
}

// ---------------- kB ----------------
__global__ __launch_bounds__(256) void kB(
    const float* __restrict__ x, const float* __restrict__ g1, const float* __restrict__ b1,
    const unsigned short* __restrict__ wbf, const unsigned short* __restrict__ Mgbf,
    const float* __restrict__ bout, const float* __restrict__ g2, const float* __restrict__ b2,
    float* __restrict__ y)
{
  __shared__ __align__(16) char smem[37632];
  unsigned short* xn_s = (unsigned short*)smem;             // [0,36864) staging (dead after bx)
  unsigned short* qs_s = (unsigned short*)smem;             // [0,20480)  alias
  float* sp            = (float*)(smem + 36864);            // 192 floats

  const int t = threadIdx.x;
  const int bid = blockIdx.x;
  const int b = bid >> 9;
  const long col0 = (long)(bid & 511) * 256;
  const int w = t >> 6, lane = t & 63, qq = lane >> 4, l16 = lane & 15;

  if (t < 64){ sp[t] = bout[t]; sp[64+t] = g2[t]; sp[128+t] = b2[t]; }
  ln_stage(x + (long)b*CH*NCOL + col0 + t, g1, b1, xn_s, t);
  // in-wave read-back of own wave's columns
  FragU bx[4][2];
  #pragma unroll
  for (int nt = 0; nt < 4; nt++)
    #pragma unroll
    for (int ks = 0; ks < 2; ks++)
      bx[nt][ks].q = *(const u32x4*)(xn_s + ((4*w+nt)*16 + l16)*72 + ks*32 + qq*8);
  __syncthreads();   // alias guard (xn -> qs) + sp visibility; ONLY barrier in kB

  floatx4 yacc[4][4];
  #pragma unroll
  for (int ot = 0; ot < 4; ot++)
    #pragma unroll
    for (int nt = 0; nt < 4; nt++)
      yacc[ot][nt] = floatx4{0.f,0.f,0.f,0.f};

  #pragma unroll
  for (int h = 0; h < 4; h++){
    // q GEMM -> exp -> in-register column softmax (shfl over qq lanes) -> qs_s
    FragU a00, a01, a10, a11;
    {
      const unsigned short* wr0 = wbf + (h*32 + l16)*64 + qq*8;
      const unsigned short* wr1 = wbf + (h*32 + 16 + l16)*64 + qq*8;
      a00.q = *(const u32x4*)wr0; a01.q = *(const u32x4*)(wr0 + 32);
      a10.q = *(const u32x4*)wr1; a11.q = *(const u32x4*)(wr1 + 32);
    }
    #pragma unroll
    for (int nt = 0; nt < 4; nt++){
      floatx4 c0 = floatx4{0.f,0.f,0.f,0.f};
      floatx4 c1 = floatx4{0.f,0.f,0.f,0.f};
      c0 = __builtin_amdgcn_mfma_f32_16x16x32_bf16(a00.v, bx[nt][0].v, c0, 0, 0, 0);
      c0 = __builtin_amdgcn_mfma_f32_16x16x32_bf16(a01.v, bx[nt][1].v, c0, 0, 0, 0);
      c1 = __builtin_amdgcn_mfma_f32_16x16x32_bf16(a10.v, bx[nt][0].v, c1, 0, 0, 0);
      c1 = __builtin_amdgcn_mfma_f32_16x16x32_bf16(a11.v, bx[nt][1].v, c1, 0, 0, 0);
      float e[8]; float s = 0.f;
      #pragma unroll
      for (int r = 0; r < 4; r++){ e[r] = __expf(c0[r]); s += e[r]; }
      #pragma unroll
      for (int r = 0; r < 4; r++){ e[4+r] = __expf(c1[r]); s += e[4+r]; }
      // column (4w+nt)*16+l16 spans lanes {l16, l16+16, l16+32, l16+48}
      s += __shfl_xor(s, 16, 64); s += __shfl_xor(s, 32, 64);
      const float sc = 0.17677669529663687f / s;   // 32^-0.5 / sum
      const int colb = (4*w+nt)*16 + l16;
      u32x2 pk0, pk1;
      pk0[0] = (unsigned)bfb(e[0]*sc) | ((unsigned)bfb(e[1]*sc) << 16);
      pk0[1] = (unsigned)bfb(e[2]*sc) | ((unsigned)bfb(e[3]*sc) << 16);
      pk1[0] = (unsigned)bfb(e[4]*sc) | ((unsigned)bfb(e[5]*sc) << 16);
      pk1[1] = (unsigned)bfb(e[6]*sc) | ((unsigned)bfb(e[7]*sc) << 16);
      *(u32x2*)(qs_s + colb*40 + qq*4)      = pk0;
      *(u32x2*)(qs_s + colb*40 + 16 + qq*4) = pk1;
    }
    // y += M_h @ qs_h  (in-wave DS ordering: qs writes above precede these reads)
    #pragma unroll
    for (int ot = 0; ot < 4; ot++){
      FragU am;
      am.q = *(const u32x4*)(Mgbf + (((long)b*4 + h)*64 + ot*16 + l16)*32 + qq*8);
      #pragma unroll
      for (int nt = 0; nt < 4; nt++){
        FragU bq; bq.q = *(const u32x4*)(qs_s + ((4*w+nt)*16 + l16)*40 + qq*8);
        yacc[ot][nt] = __builtin_amdgcn_mfma_f32_16x16x32_bf16(am.v, bq.v, yacc[ot][nt], 0, 0, 0);
      }
    }
  }

  // epilogue: +b_out, LN2 over 64 rows (rows live on lanes {l16, l16+16, l16+32, l16+48})
  const long ybase = (long)b*CH*NCOL;
  #pragma unroll
  for (int nt = 0; nt < 4; nt++){
    const long colg = col0 + (4*w+nt)*16 + l16;
    float vals[16]; float s = 0.f, ss = 0.f;
    #pragma unroll
    for (int ot = 0; ot < 4; ot++)
      #pragma unroll
      for (int r = 0; r < 4; r++){
        const float v = yacc[ot][nt][r] + sp[ot*16 + qq*4 + r];
        vals[ot*4+r] = v; s += v; ss = fmaf(v, v, ss);
      }
    s  += __shfl_xor(s, 16, 64);  s  += __shfl_xor(s, 32, 64);
    ss += __shfl_xor(ss, 16, 64); ss += __shfl_xor(ss, 32, 64);
    const float mean = s * (1.f/64.f);
    const float rstd = rsqrtf(ss * (1.f/64.f) - mean*mean + 1e-5f);
    #pragma unroll
    for (int ot = 0; ot < 4; ot++)
      #pragma unroll
      for (int r = 0; r < 4; r++){
        const int row = ot*16 + qq*4 + r;
        y[ybase + (long)row*NCOL + colg] = (vals[ot*4+r]-mean)*rstd*sp[64+row] + sp[128+row];
      }
  }
}

extern "C" void kernel_launch(void* const* d_in, const int* in_sizes, int n_in,
                              void* d_out, int out_size, void* d_ws, size_t ws_size,
                              hipStream_t stream)
{
  const float* x    = (const float*)d_in[0];
  const float* g1   = (const float*)d_in[1];
  const float* b1   = (const float*)d_in[2];
  const float* wqkv = (const float*)d_in[3];
  const float* wout = (const float*)d_in[4];
  const float* bout = (const float*)d_in[5];
  const float* g2   = (const float*)d_in[6];
  const float* b2   = (const float*)d_in[7];
  float* y  = (float*)d_out;
  float* ws = (float*)d_ws;

  float* pctx = ws;                          // [0, 4194304) floats
  float* O    = ws + 4194304;                // [4194304, 4202496)  (zeroed by kW)
  float* Zg   = O + 8192;                    // [4202496, 4202752)  (zeroed by kW)
  unsigned short* Mgbf = (unsigned short*)(Zg + 256);          // 16384 shorts -> ends 4210944 fl
  unsigned short* wbf  = (unsigned short*)(ws + 4210944);      // 24576 shorts -> ends 4223232 fl

  hipLaunchKernelGGL(kW,  dim3(96),   dim3(256), 0, stream, wqkv, wbf, O);
  hipLaunchKernelGGL(kA,  dim3(1024), dim3(256), 0, stream, x, g1, b1, wbf, pctx, Zg);
  hipLaunchKernelGGL(kR1, dim3(256),  dim3(256), 0, stream, pctx, O);
  hipLaunchKernelGGL(kM,  dim3(64),   dim3(256), 0, stream, O, Zg, wout, Mgbf);
  hipLaunchKernelGGL(kB,  dim3(1024), dim3(256), 0, stream, x, g1, b1, wbf, Mgbf, bout, g2, b2, y);
}